// Round 1
// baseline (133.623 us; speedup 1.0000x reference)
//
#include <hip/hip_runtime.h>

// Problem constants (fixed by the reference file)
constexpr int Gc = 40;      // voxel grid side
constexpr int Pc = 16;      // max points per voxel
constexpr int Kc = 32;      // neighbors out
constexpr int Bc = 4;       // batch
constexpr int Nc = 65536;   // points
constexpr int Sc = 4096;    // centroids per batch

// 32 lanes per centroid (2 centroids per wave64), branch-free except a
// rarely-taken exec-masked overflow gather:
//  - lanes 0..26 gather neighbor voxel count AND prefetch the voxel's first
//    4 point indices (dwordx4, 64B-aligned) in the same memory round-trip.
//  - inclusive shuffle-scan of counts -> per-voxel output ranges
//  - lane k binary-searches (5 shuffles) for its source voxel, then pulls
//    its point from the prefetched int4 via shuffle (j<4 covers ~99.6% of
//    voxels at lambda~1 point/voxel); only j>=4 slots do a dependent gather.
//  - XCD-affinity swizzle: batch b -> XCD pair {2b,2b+1} so each XCD's L2
//    holds one batch's voxel_points (4MB) + counts (256KB) + pos (768KB).
__global__ __launch_bounds__(256) void frnn_kernel(
    const float* __restrict__ pos,          // (B,N,3)
    const int*   __restrict__ centroids,    // (B,S)
    const int*   __restrict__ voxel_points, // (B,G,G,G,P)
    const int*   __restrict__ voxel_counts, // (B,G,G,G)
    float*       __restrict__ out)          // (B,S,K)
{
    // --- XCD-affinity block swizzle (bijective; perf-only heuristic) ---
    // blockIdx.x -> XCD is round-robin (i & 7) on MI355X. Give each batch
    // a dedicated XCD pair so its gather working set is L2-resident.
    const int i    = blockIdx.x;
    const int xcd  = i & 7;
    const int b    = xcd >> 1;                     // batch 0..3
    const int wb   = (i >> 3) * 2 + (xcd & 1);     // block-within-batch 0..511
    const int gin  = wb * 8 + (threadIdx.x >> 5);  // group-within-batch 0..4095
    const int g    = b * Sc + gin;                 // global centroid id
    const int lane = threadIdx.x & 31;             // lane within 32-lane group

    const int c = centroids[g];                    // group-uniform -> 1 request

    const float* pp = pos + ((size_t)b * Nc + (size_t)c) * 3;
    // reference: (pos * (G-1)).astype(int32) -> trunc of fp32 product
    const int vx = (int)(pp[0] * 39.0f);
    const int vy = (int)(pp[1] * 39.0f);
    const int vz = (int)(pp[2] * 39.0f);

    const int* vcnt_b = voxel_counts + (size_t)b * (Gc * Gc * Gc);
    const int* vpts_b = voxel_points + (size_t)b * (Gc * Gc * Gc) * Pc;

    // --- per-voxel count gather + first-4-points prefetch (lanes 0..26) ---
    // Both loads issue back-to-back; their latency overlaps the scan/bsearch.
    int cnt = 0, cell = 0;
    int4 pre = make_int4(0, 0, 0, 0);
    if (lane < 27) {
        int dx = lane / 9 - 1;
        int dy = (lane / 3) % 3 - 1;
        int dz = lane % 3 - 1;
        int nx = vx + dx, ny = vy + dy, nz = vz + dz;
        const bool inb = (unsigned)nx < (unsigned)Gc &&
                         (unsigned)ny < (unsigned)Gc &&
                         (unsigned)nz < (unsigned)Gc;
        cell = inb ? (nx * Gc + ny) * Gc + nz : 0;   // clamp OOB to safe cell
        int cr = vcnt_b[cell];
        pre = *reinterpret_cast<const int4*>(vpts_b + (size_t)cell * Pc);
        cnt = inb ? (cr > Pc ? Pc : cr) : 0;         // mask>0 subsumed by cnt>0
    }

    // --- inclusive scan of cnt within the 32-lane group ---
    int incl = cnt;
    #pragma unroll
    for (int off = 1; off < 32; off <<= 1) {
        int n = __shfl_up(incl, off, 32);
        if (lane >= off) incl += n;
    }
    const int excl  = incl - cnt;           // this voxel's first output slot
    const int total = __shfl(incl, 31, 32); // total candidates

    // --- branch-free binary search: v = #{i : incl[i] <= lane} ---
    int v = 0;
    #pragma unroll
    for (int s = 16; s; s >>= 1) {
        int t = __shfl(incl, v + s - 1, 32);
        v += (t <= lane) ? s : 0;
    }
    // valid lanes: v <= 26. Invalid lanes give garbage v — masked below.
    const int vm     = v & 31;              // keep shuffle index in-range
    const int excl_v = __shfl(excl, vm, 32);
    const int cell_v = __shfl(cell, vm, 32);
    const int q0     = __shfl(pre.x, vm, 32);   // independent shuffles,
    const int q1     = __shfl(pre.y, vm, 32);   // latency overlaps
    const int q2     = __shfl(pre.z, vm, 32);
    const int q3     = __shfl(pre.w, vm, 32);
    const int j      = lane - excl_v;       // slot within voxel, j < cnt[v]

    const int  tk    = total < Kc ? total : Kc;
    const bool valid = lane < tk;

    // j<4 (~99.6% of voxels at ~1 pt/voxel): value already in registers.
    int pv = (j == 1) ? q1 : (j == 2) ? q2 : (j == 3) ? q3 : q0;
    // rare overflow: dependent gather, exec-masked (skipped when no lane hits)
    if (valid && j > 3) {
        pv = vpts_b[cell_v * Pc + j];
    }

    out[(size_t)g * Kc + lane] = valid ? (float)pv : (float)c;  // pad = centroid
}

extern "C" void kernel_launch(void* const* d_in, const int* in_sizes, int n_in,
                              void* d_out, int out_size, void* d_ws, size_t ws_size,
                              hipStream_t stream) {
    const float* pos       = (const float*)d_in[0];
    const int*   centroids = (const int*)d_in[1];
    const int*   vpts      = (const int*)d_in[2];
    const int*   vcnt      = (const int*)d_in[3];
    // d_in[4] (neighbour_voxel_list) == cvid + offsets (recomputed in-kernel),
    // d_in[5] (mask) subsumed by per-point p < cnt test, d_in[6] = G (hardcoded).
    float* out = (float*)d_out;

    const int total_threads = Bc * Sc * 32;       // 32 lanes per centroid
    const int block = 256;
    const int grid  = total_threads / block;      // 2048 blocks, 32 waves/CU
    frnn_kernel<<<grid, block, 0, stream>>>(pos, centroids, vpts, vcnt, out);
}

// Round 2
// 131.697 us; speedup vs baseline: 1.0146x; 1.0146x over previous
//
#include <hip/hip_runtime.h>

// Problem constants (fixed by the reference file)
constexpr int Gc = 40;      // voxel grid side
constexpr int Pc = 16;      // max points per voxel
constexpr int Kc = 32;      // neighbors out
constexpr int Bc = 4;       // batch
constexpr int Nc = 65536;   // points
constexpr int Sc = 4096;    // centroids per batch

// 32 lanes per centroid (2 centroids per wave64), fully branch-free:
//  - lanes 0..26 gather their neighbor voxel's count (reference order:
//    v = (dx+1)*9 + (dy+1)*3 + (dz+1), row-major)
//  - inclusive shuffle-scan of counts -> per-voxel output ranges
//  - lane k binary-searches (5 shuffles) for the voxel containing output
//    slot k, gathers exactly one point index (LAZY: only lines of non-empty
//    voxels actually needed get touched -- matters because the harness's
//    324MB poison fills flush L2/L3 every iteration, so we always run cold
//    and distinct-line HBM traffic is the cost model).
//  - XCD-affinity swizzle: batch b -> XCD pair {2b,2b+1} so each XCD's L2
//    only ever requests its own batch's working set (~3.6 MB: 2.6 MB
//    voxel_points lines + 256 KB counts + 768 KB pos) instead of all 8
//    XCDs each cold-fetching a large fraction of the full 10+ MB.
__global__ __launch_bounds__(256) void frnn_kernel(
    const float* __restrict__ pos,          // (B,N,3)
    const int*   __restrict__ centroids,    // (B,S)
    const int*   __restrict__ voxel_points, // (B,G,G,G,P)
    const int*   __restrict__ voxel_counts, // (B,G,G,G)
    float*       __restrict__ out)          // (B,S,K)
{
    // --- XCD-affinity block swizzle (bijective; perf-only heuristic) ---
    // blockIdx.x -> XCD is round-robin (i & 7) on MI355X.
    const int i    = blockIdx.x;
    const int xcd  = i & 7;
    const int b    = xcd >> 1;                     // batch 0..3
    const int wb   = (i >> 3) * 2 + (xcd & 1);     // block-within-batch 0..511
    const int gin  = wb * 8 + (threadIdx.x >> 5);  // group-within-batch 0..4095
    const int g    = b * Sc + gin;                 // global centroid id
    const int lane = threadIdx.x & 31;             // lane within 32-lane group

    const int c = centroids[g];                    // group-uniform -> 1 request

    const float* pp = pos + ((size_t)b * Nc + (size_t)c) * 3;
    // reference: (pos * (G-1)).astype(int32) -> trunc of fp32 product
    const int vx = (int)(pp[0] * 39.0f);
    const int vy = (int)(pp[1] * 39.0f);
    const int vz = (int)(pp[2] * 39.0f);

    const int* vcnt_b = voxel_counts + (size_t)b * (Gc * Gc * Gc);
    const int* vpts_b = voxel_points + (size_t)b * (Gc * Gc * Gc) * Pc;

    // --- per-voxel count gather (lanes 0..26; reference scan order) ---
    int cnt = 0, cell = 0;
    if (lane < 27) {
        int dx = lane / 9 - 1;
        int dy = (lane / 3) % 3 - 1;
        int dz = lane % 3 - 1;
        int nx = vx + dx, ny = vy + dy, nz = vz + dz;
        if ((unsigned)nx < (unsigned)Gc && (unsigned)ny < (unsigned)Gc &&
            (unsigned)nz < (unsigned)Gc) {
            cell = (nx * Gc + ny) * Gc + nz;
            cnt  = vcnt_b[cell];
            if (cnt > Pc) cnt = Pc;         // mask>0 subsumed by cnt>0
        }
    }

    // --- inclusive scan of cnt within the 32-lane group ---
    int incl = cnt;
    #pragma unroll
    for (int off = 1; off < 32; off <<= 1) {
        int n = __shfl_up(incl, off, 32);
        if (lane >= off) incl += n;
    }
    const int excl  = incl - cnt;           // this voxel's first output slot
    const int total = __shfl(incl, 31, 32); // total candidates

    // --- branch-free binary search: v = #{i : incl[i] <= lane} ---
    // incl is non-decreasing across lanes, so v is the voxel whose output
    // range [excl[v], incl[v]) contains slot `lane` (when lane < total).
    int v = 0;
    #pragma unroll
    for (int s = 16; s; s >>= 1) {
        int t = __shfl(incl, v + s - 1, 32);
        v += (t <= lane) ? s : 0;
    }
    // For valid lanes v <= 26 (incl[26] == total > lane). Invalid lanes give
    // garbage v (possibly 32) — masked below; & 31 keeps the shuffle in-range.
    const int excl_v = __shfl(excl, v & 31, 32);
    const int cell_v = __shfl(cell, v & 31, 32);
    const int j      = lane - excl_v;       // j < cnt[v] <= P for valid lanes
    const int idx    = cell_v * Pc + j;     // flat index into voxel_points[b]

    const int  tk    = total < Kc ? total : Kc;
    const bool valid = lane < tk;
    const int  sidx  = valid ? idx : 0;     // clamp garbage to a safe address
    const float pv   = (float)vpts_b[sidx]; // lazy gather: only needed lines
    out[(size_t)g * Kc + lane] = valid ? pv : (float)c;  // pad with centroid
}

extern "C" void kernel_launch(void* const* d_in, const int* in_sizes, int n_in,
                              void* d_out, int out_size, void* d_ws, size_t ws_size,
                              hipStream_t stream) {
    const float* pos       = (const float*)d_in[0];
    const int*   centroids = (const int*)d_in[1];
    const int*   vpts      = (const int*)d_in[2];
    const int*   vcnt      = (const int*)d_in[3];
    // d_in[4] (neighbour_voxel_list) == cvid + offsets (recomputed in-kernel),
    // d_in[5] (mask) subsumed by per-point p < cnt test, d_in[6] = G (hardcoded).
    float* out = (float*)d_out;

    const int total_threads = Bc * Sc * 32;       // 32 lanes per centroid
    const int block = 256;
    const int grid  = total_threads / block;      // 2048 blocks, 32 waves/CU
    frnn_kernel<<<grid, block, 0, stream>>>(pos, centroids, vpts, vcnt, out);
}